// Round 4
// baseline (337.205 us; speedup 1.0000x reference)
//
#include <hip/hip_runtime.h>

typedef _Float16 half8 __attribute__((ext_vector_type(8)));
typedef float f32x4 __attribute__((ext_vector_type(4)));

#define NB 2
#define LS 4800
#define CCH 256
#define W0 80
#define W1 80
#define THRV 0.2f
#define SQS 0.19764235376052370f   // sqrt(1/(C*TEMP)) = sqrt(1/25.6)

#define TN 38          // tiles per dim -> padded 4864
#define PADL 4864

// ---- ws float offsets ----
#define OF_RM   0           // [NB*LS] sim row max
#define OF_RSI  9600        // [NB*LS] 1/row sumexp
#define OF_CM   19200       // [NB*LS] sim col max
#define OF_CSI  28800       // [NB*LS] 1/col sumexp
#define OF_RWM  38400       // [NB*LS] conf row max
#define OF_CAND 48000       // [NB*LS] (int) argmax col of conf row
#define OF_CLM  57600       // [NB*LS] conf col max
#define OF_PROW 67200                    // float2 [NB][TN][PADL] sim row partials (m,s)
#define OF_PCOL (OF_PROW + 739328)       // float2 [NB][TN][PADL] sim col partials
#define OF_PRWM (OF_PCOL + 739328)       // float2 [NB][TN][PADL] conf row (max, idx)
#define OF_PCLM (OF_PRWM + 739328)       // float  [NB][TN][PADL] conf col max
#define OF_AH   (OF_PCLM + 369664)       // _Float16 [NB][LS][CCH]
#define OF_BH   (OF_AH + 1228800)
// end = OF_BH + 1228800 = ~20.4 MB of d_ws

// ---- out float offsets (conf, mask_v, j_ids, mkpts1_c, mconf) ----
#define O_MASKV 46080000ull
#define O_JIDS  46089600ull
#define O_MKPT  46099200ull
#define O_MCONF 46118400ull

__device__ __forceinline__ void load_lds16(const void* g, void* l) {
    __builtin_amdgcn_global_load_lds((const __attribute__((address_space(1))) void*)g,
                                     (__attribute__((address_space(3))) void*)l, 16, 0, 0);
}

// --------------------------------------------------------- f32 -> f16 cast --
__global__ __launch_bounds__(256) void conv_half(const float* __restrict__ A,
                                                 const float* __restrict__ B,
                                                 float* __restrict__ ws) {
    const int which = blockIdx.y;
    const float* src = which ? B : A;
    _Float16* dst = (_Float16*)(ws + (which ? OF_BH : OF_AH));
    const int idx = blockIdx.x * 256 + threadIdx.x;   // float4 index, 614400 total
    const float4 v = ((const float4*)src)[idx];
    union { _Float16 h[4]; uint2 u; } p;
    p.h[0] = (_Float16)(v.x * SQS);
    p.h[1] = (_Float16)(v.y * SQS);
    p.h[2] = (_Float16)(v.z * SQS);
    p.h[3] = (_Float16)(v.w * SQS);
    ((uint2*)dst)[idx] = p.u;
}

// Shared K-loop: computes the 128x128 tile's 4x4 f32x4 accumulators.
// LDS slot(row,q) = row*8 + (q ^ (row&7)); coalesced staging AND conflict-free
// ds_read_b128 fragment reads.
#define GEMM_KLOOP(SMEM)                                                        \
    const int lane = tid & 63, w = tid >> 6;                                    \
    const int wx = w & 1, wy = w >> 1;                                          \
    const int m = lane & 15, quad = lane >> 4;                                  \
    f32x4 acc[4][4];                                                            \
    {                                                                           \
        f32x4 z = {0.f, 0.f, 0.f, 0.f};                                        \
        for (int a = 0; a < 4; a++)                                             \
            for (int b = 0; b < 4; b++) acc[a][b] = z;                          \
    }                                                                           \
    const int srow = lane >> 3;                                                 \
    const int qst = (lane & 7) ^ (srow & 7);                                    \
    for (int kt = 0; kt < 4; kt++) {                                            \
        const int k0 = kt * 64;                                                 \
        _Pragma("unroll")                                                       \
        for (int i = 0; i < 4; i++) {                                           \
            const int c = i * 4 + w;                                            \
            int gr = by * 128 + c * 8 + srow; gr = gr < LS ? gr : LS - 1;       \
            load_lds16(Ah + (size_t)gr * CCH + k0 + qst * 8, &SMEM.st.A[c * 512]); \
        }                                                                       \
        _Pragma("unroll")                                                       \
        for (int i = 0; i < 4; i++) {                                           \
            const int c = i * 4 + w;                                            \
            int gr = bx * 128 + c * 8 + srow; gr = gr < LS ? gr : LS - 1;       \
            load_lds16(Bh + (size_t)gr * CCH + k0 + qst * 8, &SMEM.st.B[c * 512]); \
        }                                                                       \
        __syncthreads();                                                        \
        _Pragma("unroll")                                                       \
        for (int t = 0; t < 2; t++) {                                           \
            half8 Af[4], Bf[4];                                                 \
            _Pragma("unroll")                                                   \
            for (int a = 0; a < 4; a++) {                                       \
                const int rl = wy * 64 + a * 16 + m;                            \
                const int sl = rl * 8 + ((t * 4 + quad) ^ (rl & 7));            \
                Af[a] = *(const half8*)&SMEM.st.A[sl * 8];                      \
            }                                                                   \
            _Pragma("unroll")                                                   \
            for (int b = 0; b < 4; b++) {                                       \
                const int cl = wx * 64 + b * 16 + m;                            \
                const int sl = cl * 8 + ((t * 4 + quad) ^ (cl & 7));            \
                Bf[b] = *(const half8*)&SMEM.st.B[sl * 8];                      \
            }                                                                   \
            _Pragma("unroll")                                                   \
            for (int a = 0; a < 4; a++)                                         \
                _Pragma("unroll")                                               \
                for (int b = 0; b < 4; b++)                                     \
                    acc[a][b] = __builtin_amdgcn_mfma_f32_16x16x32_f16(Af[a], Bf[b], acc[a][b], 0, 0, 0); \
        }                                                                       \
        __syncthreads();                                                        \
    }

// ------------------------------ pass A: sim softmax stat partials only ------
__global__ __launch_bounds__(256, 2) void gemm_stats(float* __restrict__ ws) {
    __shared__ __align__(16) union {
        struct { _Float16 A[8192]; _Float16 B[8192]; } st;
        struct { float rs[128][2][2]; float cs[128][2][2]; } red;
    } sm;
    const int bx = blockIdx.x, by = blockIdx.y, n = blockIdx.z;
    const _Float16* Ah = (const _Float16*)(ws + OF_AH) + (size_t)n * LS * CCH;
    const _Float16* Bh = (const _Float16*)(ws + OF_BH) + (size_t)n * LS * CCH;
    const int tid = threadIdx.x;

    GEMM_KLOOP(sm)

    const int l0 = by * 128, s0 = bx * 128;
    bool bval[4];
#pragma unroll
    for (int b = 0; b < 4; b++) bval[b] = (s0 + wx * 64 + b * 16 + m) < LS;
    bool aval[4][4];
#pragma unroll
    for (int a = 0; a < 4; a++)
#pragma unroll
        for (int reg = 0; reg < 4; reg++)
            aval[a][reg] = (l0 + wy * 64 + a * 16 + quad * 4 + reg) < LS;

#pragma unroll
    for (int a = 0; a < 4; a++) {
#pragma unroll
        for (int reg = 0; reg < 4; reg++) {
            float mx = -1e30f;
#pragma unroll
            for (int b = 0; b < 4; b++) if (bval[b]) mx = fmaxf(mx, acc[a][b][reg]);
            for (int d = 1; d < 16; d <<= 1) mx = fmaxf(mx, __shfl_xor(mx, d, 64));
            float sum = 0.f;
#pragma unroll
            for (int b = 0; b < 4; b++) if (bval[b]) sum += __expf(acc[a][b][reg] - mx);
            for (int d = 1; d < 16; d <<= 1) sum += __shfl_xor(sum, d, 64);
            if (m == 0) {
                const int rl = wy * 64 + a * 16 + quad * 4 + reg;
                sm.red.rs[rl][wx][0] = mx; sm.red.rs[rl][wx][1] = sum;
            }
        }
    }
#pragma unroll
    for (int b = 0; b < 4; b++) {
        float mx = -1e30f;
#pragma unroll
        for (int a = 0; a < 4; a++)
#pragma unroll
            for (int reg = 0; reg < 4; reg++)
                if (aval[a][reg]) mx = fmaxf(mx, acc[a][b][reg]);
        float sum = 0.f;
#pragma unroll
        for (int a = 0; a < 4; a++)
#pragma unroll
            for (int reg = 0; reg < 4; reg++)
                if (aval[a][reg]) sum += __expf(acc[a][b][reg] - mx);
        for (int d = 16; d < 64; d <<= 1) {
            const float mo = __shfl_xor(mx, d, 64);
            const float so = __shfl_xor(sum, d, 64);
            const float nm = fmaxf(mx, mo);
            sum = sum * __expf(mx - nm) + so * __expf(mo - nm);
            mx = nm;
        }
        if (quad == 0) {
            const int cl = wx * 64 + b * 16 + m;
            sm.red.cs[cl][wy][0] = mx; sm.red.cs[cl][wy][1] = sum;
        }
    }
    __syncthreads();
    if (tid < 128) {
        const float m0 = sm.red.rs[tid][0][0], v0 = sm.red.rs[tid][0][1];
        const float m1 = sm.red.rs[tid][1][0], v1 = sm.red.rs[tid][1][1];
        const float nm = fmaxf(m0, m1);
        const float s = v0 * __expf(m0 - nm) + v1 * __expf(m1 - nm);
        ((float2*)(ws + OF_PROW))[((size_t)n * TN + bx) * PADL + by * 128 + tid] = make_float2(nm, s);
    } else {
        const int t = tid - 128;
        const float m0 = sm.red.cs[t][0][0], v0 = sm.red.cs[t][0][1];
        const float m1 = sm.red.cs[t][1][0], v1 = sm.red.cs[t][1][1];
        const float nm = fmaxf(m0, m1);
        const float s = v0 * __expf(m0 - nm) + v1 * __expf(m1 - nm);
        ((float2*)(ws + OF_PCOL))[((size_t)n * TN + by) * PADL + bx * 128 + t] = make_float2(nm, s);
    }
}

// -------------------------------------------------- combine 38 partials -----
__global__ __launch_bounds__(256) void combine_stats(float* __restrict__ ws) {
    const int idx = blockIdx.x * 256 + threadIdx.x;   // 19200 total
    if (idx >= 2 * NB * LS) return;
    const int half_ = idx >= 9600;
    const int i = idx - half_ * 9600;
    const int n = i / LS, r = i % LS;
    const float2* P = (const float2*)(ws + (half_ ? OF_PCOL : OF_PROW)) + (size_t)n * TN * PADL + r;
    float M = -1e30f, S = 0.f;
    for (int b = 0; b < TN; b++) {
        const float2 p = P[(size_t)b * PADL];
        const float nm = fmaxf(M, p.x);
        S = S * __expf(M - nm) + p.y * __expf(p.x - nm);
        M = nm;
    }
    if (!half_) { ws[OF_RM + i] = M; ws[OF_RSI + i] = 1.0f / S; }
    else        { ws[OF_CM + i] = M; ws[OF_CSI + i] = 1.0f / S; }
}

// --------------- pass B: recompute GEMM, write conf, conf max partials ------
__global__ __launch_bounds__(256, 2) void gemm_conf(float* __restrict__ out,
                                                    float* __restrict__ ws) {
    __shared__ __align__(16) union {
        struct { _Float16 A[8192]; _Float16 B[8192]; } st;
        struct {
            float rowst[128][2];   // rm, rsi
            float colst[128][2];   // cm, csi
            float rv[128][2][2];   // conf row (max, idx) per wx
            float cv[128][2];      // conf col max per wy
        } ep;
    } sm;
    const int bx = blockIdx.x, by = blockIdx.y, n = blockIdx.z;
    const _Float16* Ah = (const _Float16*)(ws + OF_AH) + (size_t)n * LS * CCH;
    const _Float16* Bh = (const _Float16*)(ws + OF_BH) + (size_t)n * LS * CCH;
    const int tid = threadIdx.x;

    GEMM_KLOOP(sm)

    const int l0 = by * 128, s0 = bx * 128;
    // stage finalized stats into LDS (FIX: compute local index first, THEN clamp)
    if (tid < 128) {
        int gr = l0 + tid; gr = gr < LS ? gr : LS - 1;
        sm.ep.rowst[tid][0] = ws[OF_RM + n * LS + gr];
        sm.ep.rowst[tid][1] = ws[OF_RSI + n * LS + gr];
    } else {
        const int lc = tid - 128;
        int gc = s0 + lc; gc = gc < LS ? gc : LS - 1;
        sm.ep.colst[lc][0] = ws[OF_CM + n * LS + gc];
        sm.ep.colst[lc][1] = ws[OF_CSI + n * LS + gc];
    }
    __syncthreads();

    float* On = out + (size_t)n * LS * LS;
    bool bval[4]; int gcol[4];
#pragma unroll
    for (int b = 0; b < 4; b++) {
        gcol[b] = s0 + wx * 64 + b * 16 + m;
        bval[b] = gcol[b] < LS;
    }
    // transform acc -> conf, store
#pragma unroll
    for (int a = 0; a < 4; a++) {
        const int lr0 = wy * 64 + a * 16 + quad * 4;
#pragma unroll
        for (int reg = 0; reg < 4; reg++) {
            const int lr = lr0 + reg;
            const float rm = sm.ep.rowst[lr][0], rsi = sm.ep.rowst[lr][1];
            const bool rok = (l0 + lr) < LS;
#pragma unroll
            for (int b = 0; b < 4; b++) {
                const int lc = wx * 64 + b * 16 + m;
                const float cmv = sm.ep.colst[lc][0], csi = sm.ep.colst[lc][1];
                const float x = acc[a][b][reg];
                const float c = __expf(2.f * x - rm - cmv) * (rsi * csi);
                acc[a][b][reg] = c;
                if (rok && bval[b]) On[(size_t)(l0 + lr) * LS + gcol[b]] = c;
            }
        }
    }

    // conf row max + argmax (global col), per (a,reg) row
#pragma unroll
    for (int a = 0; a < 4; a++) {
#pragma unroll
        for (int reg = 0; reg < 4; reg++) {
            float v = -1.f; int ii = 0;
#pragma unroll
            for (int b = 0; b < 4; b++) {
                if (bval[b]) {
                    const float c = acc[a][b][reg];
                    if (c > v) { v = c; ii = gcol[b]; }
                }
            }
            for (int d = 1; d < 16; d <<= 1) {
                const float vo = __shfl_xor(v, d, 64);
                const int io = __shfl_xor(ii, d, 64);
                if (vo > v || (vo == v && io < ii)) { v = vo; ii = io; }
            }
            if (m == 0) {
                const int rl = wy * 64 + a * 16 + quad * 4 + reg;
                sm.ep.rv[rl][wx][0] = v;
                sm.ep.rv[rl][wx][1] = __int_as_float(ii);
            }
        }
    }
    // conf col max per b
    bool aval[4][4];
#pragma unroll
    for (int a = 0; a < 4; a++)
#pragma unroll
        for (int reg = 0; reg < 4; reg++)
            aval[a][reg] = (l0 + wy * 64 + a * 16 + quad * 4 + reg) < LS;
#pragma unroll
    for (int b = 0; b < 4; b++) {
        float v = -1.f;
#pragma unroll
        for (int a = 0; a < 4; a++)
#pragma unroll
            for (int reg = 0; reg < 4; reg++)
                if (aval[a][reg]) v = fmaxf(v, acc[a][b][reg]);
        for (int d = 16; d < 64; d <<= 1) v = fmaxf(v, __shfl_xor(v, d, 64));
        if (quad == 0) {
            const int cl = wx * 64 + b * 16 + m;
            sm.ep.cv[cl][wy] = v;
        }
    }
    __syncthreads();
    if (tid < 128) {
        const float v0 = sm.ep.rv[tid][0][0], v1 = sm.ep.rv[tid][1][0];
        const int i0 = __float_as_int(sm.ep.rv[tid][0][1]);
        const int i1 = __float_as_int(sm.ep.rv[tid][1][1]);
        float v; int ii;
        if (v1 > v0 || (v1 == v0 && i1 < i0)) { v = v1; ii = i1; } else { v = v0; ii = i0; }
        ((float2*)(ws + OF_PRWM))[((size_t)n * TN + bx) * PADL + by * 128 + tid] =
            make_float2(v, __int_as_float(ii));
    } else {
        const int t = tid - 128;
        (ws + OF_PCLM)[((size_t)n * TN + by) * PADL + bx * 128 + t] =
            fmaxf(sm.ep.cv[t][0], sm.ep.cv[t][1]);
    }
}

// ------------------------------------- combine conf partials over tiles -----
__global__ __launch_bounds__(256) void combine2(float* __restrict__ ws) {
    const int idx = blockIdx.x * 256 + threadIdx.x;   // 19200 total
    if (idx >= 2 * NB * LS) return;
    const int half_ = idx >= 9600;
    const int i = idx - half_ * 9600;
    const int n = i / LS, r = i % LS;
    if (!half_) {
        const float2* P = (const float2*)(ws + OF_PRWM) + (size_t)n * TN * PADL + r;
        float v = -1.f; int ii = 0;
        for (int b = 0; b < TN; b++) {
            const float2 p = P[(size_t)b * PADL];
            const int pi = __float_as_int(p.y);
            if (p.x > v || (p.x == v && pi < ii)) { v = p.x; ii = pi; }
        }
        ws[OF_RWM + i] = v;
        ((int*)ws)[OF_CAND + i] = ii;
    } else {
        const float* P = ws + OF_PCLM + (size_t)n * TN * PADL + r;
        float v = -1.f;
        for (int b = 0; b < TN; b++) v = fmaxf(v, P[(size_t)b * PADL]);
        ws[OF_CLM + i] = v;
    }
}

// ------------------------------------------------------------- matching -----
__global__ __launch_bounds__(256) void match_pass(const float* __restrict__ ws,
                                                  float* __restrict__ out) {
    const int idx = blockIdx.x * 256 + threadIdx.x;
    if (idx >= NB * LS) return;
    const int n = idx / LS, l = idx % LS;
    const float rwm = ws[OF_RWM + idx];
    const int cand = ((const int*)ws)[OF_CAND + idx];
    const float clm = ws[OF_CLM + n * LS + cand];
    const int y0 = l / W0, x0 = l % W0;
    const int y1 = cand / W1, x1 = cand % W1;
    const bool b0 = (y0 >= 2 && y0 < 58 && x0 >= 2 && x0 < 78);
    const bool b1 = (y1 >= 2 && y1 < 58 && x1 >= 2 && x1 < 78);
    const bool matched = (rwm > THRV) && b0 && b1 && (rwm == clm);
    const int j = matched ? cand : 0;
    out[O_MASKV + idx] = matched ? 1.f : 0.f;
    out[O_JIDS + idx] = (float)j;
    out[O_MKPT + (size_t)idx * 2 + 0] = (float)(j % W1);
    out[O_MKPT + (size_t)idx * 2 + 1] = (float)(j / W1);
    out[O_MCONF + idx] = matched ? rwm : 0.f;
}

// -------------------------------------------------------------- launch ------
extern "C" void kernel_launch(void* const* d_in, const int* in_sizes, int n_in,
                              void* d_out, int out_size, void* d_ws, size_t ws_size,
                              hipStream_t stream) {
    const float* f0 = (const float*)d_in[0];
    const float* f1 = (const float*)d_in[1];
    float* out = (float*)d_out;
    float* ws = (float*)d_ws;

    conv_half<<<dim3(2400, 2), 256, 0, stream>>>(f0, f1, ws);
    gemm_stats<<<dim3(TN, TN, NB), 256, 0, stream>>>(ws);
    combine_stats<<<75, 256, 0, stream>>>(ws);
    gemm_conf<<<dim3(TN, TN, NB), 256, 0, stream>>>(out, ws);
    combine2<<<75, 256, 0, stream>>>(ws);
    match_pass<<<38, 256, 0, stream>>>(ws, out);
}